// Round 4
// baseline (147.345 us; speedup 1.0000x reference)
//
#include <hip/hip_runtime.h>
#include <stdint.h>

// Sampler: temperature -> top-k -> top-p -> softmax -> multinomial (threefry)
// Round-4: k_pass1 single streaming HBM pass (optimistic >=8.0 collect, hist
// over ~143 buffered elems only; full-hist fallback for rare blocks).
// k_tail: no hist/suffix-scan — direct rank-sort of ~600 candidates.

#define BINS     4096
#define S_CHUNKS 8
#define PB       256
#define SEG      256
#define CAPT     (S_CHUNKS * SEG)
#define TB       1024
#define TOPP     0.9f
#define TOPT_F   8.0f
#define TOPT_BIN 3088   // orderKey(8.0f) >> 20

// Order-preserving float -> uint map (ascending float == ascending uint)
__device__ __forceinline__ unsigned orderKey(float x) {
  unsigned u = __float_as_uint(x);
  return (u & 0x80000000u) ? ~u : (u | 0x80000000u);
}

// JAX threefry2x32 (20 rounds), exact.
__device__ __forceinline__ void threefry2x32(unsigned k0, unsigned k1,
                                             unsigned x0, unsigned x1,
                                             unsigned &o0, unsigned &o1) {
  unsigned k2 = k0 ^ k1 ^ 0x1BD11BDAu;
  x0 += k0; x1 += k1;
#define TFR(rr) { x0 += x1; x1 = (x1 << (rr)) | (x1 >> (32 - (rr))); x1 ^= x0; }
  TFR(13) TFR(15) TFR(26) TFR(6)
  x0 += k1; x1 += k2 + 1u;
  TFR(17) TFR(29) TFR(16) TFR(24)
  x0 += k2; x1 += k0 + 2u;
  TFR(13) TFR(15) TFR(26) TFR(6)
  x0 += k0; x1 += k1 + 3u;
  TFR(17) TFR(29) TFR(16) TFR(24)
  x0 += k1; x1 += k2 + 4u;
  TFR(13) TFR(15) TFR(26) TFR(6)
  x0 += k2; x1 += k0 + 5u;
#undef TFR
  o0 = x0; o1 = x1;
}

// ---- Kernel 1: one streaming pass + tiny LDS select (fallback: 2 passes) ----
__global__ __launch_bounds__(PB) void k_pass1(
    const float* __restrict__ logits, const int* __restrict__ topk_ptr,
    int* __restrict__ scnt, float* __restrict__ svals, int* __restrict__ sidxs,
    int V) {
  __shared__ unsigned hist[BINS];   // 16 KB
  __shared__ float    lval[SEG];
  __shared__ int      lidx[SEG];
  __shared__ unsigned psum[PB];
  __shared__ unsigned lcnt, ocnt;
  __shared__ int      s_maxb, s_bstar, s_g;

  const int row = blockIdx.y, chunk = blockIdx.x, tid = threadIdx.x;
  const float* __restrict__ rp = logits + (size_t)row * (size_t)V;
  const float4* __restrict__ rp4 = (const float4*)rp;
  const int V4 = V >> 2;
  const int beg = (int)((long long)chunk * V4 / S_CHUNKS);
  const int end = (int)((long long)(chunk + 1) * V4 / S_CHUNKS);
  const bool last = (chunk == S_CHUNKS - 1);
  const int rembeg = V4 << 2;
  const int sb = row * S_CHUNKS + chunk;
  float* __restrict__ ov = svals + (size_t)sb * SEG;
  int*   __restrict__ oi = sidxs + (size_t)sb * SEG;

  for (int i = tid; i < BINS; i += PB) hist[i] = 0u;
  if (tid == 0) { lcnt = 0u; ocnt = 0u; s_maxb = -1; s_bstar = -1; }
  __syncthreads();

  // ---- scan 1 (HBM): optimistic collect of x >= TOPT_F ----
  for (int i = beg + tid; i < end; i += PB) {
    float4 v = rp4[i];
    float vv[4] = {v.x, v.y, v.z, v.w};
#pragma unroll
    for (int c = 0; c < 4; ++c) {
      if (vv[c] >= TOPT_F) {
        unsigned pos = atomicAdd(&lcnt, 1u);
        if (pos < SEG) { lval[pos] = vv[c]; lidx[pos] = (i << 2) + c; }
      }
    }
  }
  if (last) {
    for (int i = rembeg + tid; i < V; i += PB) {
      float x = rp[i];
      if (x >= TOPT_F) {
        unsigned pos = atomicAdd(&lcnt, 1u);
        if (pos < SEG) { lval[pos] = x; lidx[pos] = i; }
      }
    }
  }
  __syncthreads();

  int k = topk_ptr[0];
  if (k < 1) k = 1;
  if (k > V) k = V;
  const int ec = (end - beg) * 4 + (last ? (V - rembeg) : 0);
  const int keff = (k < ec) ? k : ec;

  const unsigned total = lcnt;
  const bool fast = (total >= (unsigned)keff) && (total <= (unsigned)SEG);

  if (fast) {
    // hist over the ~143 buffered elements only
    for (int i = tid; i < (int)total; i += PB) {
      int b = (int)(orderKey(lval[i]) >> 20);
      atomicAdd(&hist[b], 1u);
      atomicMax(&s_maxb, b);
    }
    __syncthreads();
    if (tid == 0) {
      unsigned cum = 0;
      int bstar = -1;
      for (int b = s_maxb; b >= TOPT_BIN; --b) {   // ~8 nonempty bins
        cum += hist[b];
        if (cum >= (unsigned)keff) { bstar = b; break; }
      }
      // need bstar > TOPT_BIN so (bstar<<20)-4 stays inside buffered range
      s_bstar = (bstar > TOPT_BIN) ? bstar : -1;
    }
    __syncthreads();
    if (s_bstar >= 0) {
      const unsigned ukey = ((unsigned)s_bstar << 20) - 4u; // 4-ULP tie margin
      for (int i = tid; i < (int)total; i += PB) {
        float x = lval[i];
        if (orderKey(x) >= ukey) {
          unsigned pos = atomicAdd(&ocnt, 1u);
          ov[pos] = x;
          oi[pos] = lidx[i];
        }
      }
      __syncthreads();
      if (tid == 0) scnt[sb] = (int)ocnt;
      return;
    }
    // demoted (kth at/below 8.0 boundary): re-zero dirty hist, fall through
    for (int i = tid; i < BINS; i += PB) hist[i] = 0u;
    __syncthreads();
  }

  // ---- fallback: full-chunk histogram (L2-warm re-read) ----
  for (int i = beg + tid; i < end; i += PB) {
    float4 v = rp4[i];
    atomicAdd(&hist[orderKey(v.x) >> 20], 1u);
    atomicAdd(&hist[orderKey(v.y) >> 20], 1u);
    atomicAdd(&hist[orderKey(v.z) >> 20], 1u);
    atomicAdd(&hist[orderKey(v.w) >> 20], 1u);
  }
  if (last)
    for (int i = rembeg + tid; i < V; i += PB)
      atomicAdd(&hist[orderKey(rp[i]) >> 20], 1u);
  __syncthreads();

  const int C = BINS / PB;  // 16
  {
    unsigned s = 0;
#pragma unroll
    for (int j = 0; j < C; ++j) s += hist[tid * C + j];
    psum[tid] = s;
  }
  __syncthreads();
  // parallel reverse inclusive scan: psum[t] = sum_{t'>=t} psum[t']
  for (int d = 1; d < PB; d <<= 1) {
    unsigned v = psum[tid];
    unsigned w = (tid + d < PB) ? psum[tid + d] : 0u;
    __syncthreads();
    psum[tid] = v + w;
    __syncthreads();
  }
  if (psum[tid] >= (unsigned)keff &&
      (tid == PB - 1 || psum[tid + 1] < (unsigned)keff))
    s_g = tid;  // unique boundary (psum non-increasing)
  __syncthreads();
  if (tid == 0) {
    int g = s_g;
    unsigned cum = (g < PB - 1) ? psum[g + 1] : 0u;
    int bstar = g * C;
    for (int b = g * C + C - 1; b >= g * C; --b) {
      cum += hist[b];
      if (cum >= (unsigned)keff) { bstar = b; break; }
    }
    s_bstar = bstar;
  }
  __syncthreads();
  {
    unsigned uk = (unsigned)s_bstar << 20;
    const unsigned ukey = (uk >= 4u) ? uk - 4u : 0u;  // 4-ULP tie margin
    for (int i = beg + tid; i < end; i += PB) {
      float4 v = rp4[i];
      float vv[4] = {v.x, v.y, v.z, v.w};
#pragma unroll
      for (int c = 0; c < 4; ++c) {
        if (orderKey(vv[c]) >= ukey) {
          unsigned pos = atomicAdd(&ocnt, 1u);
          if (pos < SEG) { ov[pos] = vv[c]; oi[pos] = (i << 2) + c; }
        }
      }
    }
    if (last)
      for (int i = rembeg + tid; i < V; i += PB) {
        float x = rp[i];
        if (orderKey(x) >= ukey) {
          unsigned pos = atomicAdd(&ocnt, 1u);
          if (pos < SEG) { ov[pos] = x; oi[pos] = i; }
        }
      }
    __syncthreads();
    if (tid == 0) {
      unsigned t = ocnt;
      scnt[sb] = (int)((t > (unsigned)SEG) ? (unsigned)SEG : t);
    }
  }
}

// ---- Kernel 2: merge segments, sort, top-k ties, top-p, softmax, sample ----
__global__ __launch_bounds__(TB) void k_tail(
    const int* __restrict__ scnt, const float* __restrict__ svals,
    const int* __restrict__ sidxs, const int* __restrict__ topk_ptr,
    int* __restrict__ out, int V) {
  __shared__ float cval[CAPT];  // scaled candidates (arrival order)
  __shared__ int   cidx[CAPT];
  __shared__ float sval[CAPT];  // sorted scaled
  __shared__ int   sidx[CAPT];
  __shared__ float ev[CAPT];    // exp(v - max)
  __shared__ short ord[CAPT];
  __shared__ int   s_off[S_CHUNKS + 1];
  __shared__ int   s_ns, s_K;
  __shared__ float s_S2, s_r;

  const int row = blockIdx.x, tid = threadIdx.x;
  int k = topk_ptr[0];
  if (k < 1) k = 1;
  if (k > V) k = V;

  if (tid < S_CHUNKS) s_off[tid + 1] = scnt[row * S_CHUNKS + tid];
  if (tid == 0) s_off[0] = 0;
  __syncthreads();
  if (tid == 0)
    for (int c = 1; c <= S_CHUNKS; ++c) s_off[c] += s_off[c - 1];
  __syncthreads();
  const int n = s_off[S_CHUNKS];

  if (n == 0) {  // unreachable for real data; guard
    if (tid == 0) out[row] = V;
    return;
  }

  // gather + temperature scale (IEEE div, matches ref)
  for (int i = tid; i < n; i += TB) {
    int c = 0;
    while (c < S_CHUNKS - 1 && i >= s_off[c + 1]) ++c;
    const int j = i - s_off[c];
    const size_t base = (size_t)(row * S_CHUNKS + c) * SEG;
    cval[i] = svals[base + j] / 0.8f;
    cidx[i] = sidxs[base + j];
  }
  __syncthreads();

  // rank-sort: scaled desc, index asc == ref's stable argsort(-logits)
  for (int i = tid; i < n; i += TB) {
    float v = cval[i];
    int   id = cidx[i];
    int   rk = 0;
#pragma unroll 4
    for (int j = 0; j < n; ++j) {
      float vj = cval[j];
      rk += (vj > v) || (vj == v && cidx[j] < id);
    }
    sval[rk] = v;
    sidx[rk] = id;
  }
  __syncthreads();

  // top-k survivor count (keep ties at the k-th scaled value)
  const int kk = (k < n) ? k : n;
  if (tid == 0) {
    int ns = kk;
    float kv = sval[kk - 1];
    while (ns < n && sval[ns] == kv) ++ns;
    s_ns = ns;
  }
  __syncthreads();
  const int ns = s_ns;

  const float mx = sval[0];
  for (int i = tid; i < ns; i += TB) ev[i] = expf(sval[i] - mx);
  __syncthreads();

  // top-p keep-prefix + RNG (serial ~60 iters, exact accumulation order)
  if (tid == 0) {
    float S = 0.f;
    for (int i = 0; i < ns; ++i) S += ev[i];
    float c = 0.f;
    int K = ns;
    for (int i = 0; i < ns; ++i) {
      if (i > 0 && c > TOPP) { K = i; break; }  // remove[i] = cdf[i-1] > p
      c += ev[i] / S;
    }
    float S2 = 0.f;
    for (int i = 0; i < K; ++i) S2 += ev[i];
    s_K = K;
    s_S2 = S2;

    // r = uniform from fold_in(key(0), 1), partitionable threefry path
    unsigned kk0, kk1, o0, o1;
    threefry2x32(0u, 0u, 0u, 1u, kk0, kk1);
    threefry2x32(kk0, kk1, 0u, (unsigned)row, o0, o1);
    unsigned bits = o0 ^ o1;
    float r = __uint_as_float((bits >> 9) | 0x3F800000u) - 1.0f;
    s_r = (r < 0.f) ? 0.f : r;
  }
  __syncthreads();
  const int K = s_K;

  // rank kept tokens by original index
  for (int i = tid; i < K; i += TB) {
    int id = sidx[i];
    int rk = 0;
    for (int j = 0; j < K; ++j) rk += (sidx[j] < id);
    ord[rk] = (short)i;
  }
  __syncthreads();

  // inverse-CDF sample in original-index order
  if (tid == 0) {
    const float S2 = s_S2;
    const float rr = s_r;
    float c = 0.f;
    int ans = V;  // matches sum(cdf <= r) when r beyond total mass
    for (int t = 0; t < K; ++t) {
      int i = ord[t];
      c += ev[i] / S2;
      if (c > rr) { ans = sidx[i]; break; }
    }
    out[row] = ans;
  }
}

extern "C" void kernel_launch(void* const* d_in, const int* in_sizes, int n_in,
                              void* d_out, int out_size, void* d_ws, size_t ws_size,
                              hipStream_t stream) {
  const float* logits = (const float*)d_in[0];
  const int*   topk   = (const int*)d_in[1];
  int*         out    = (int*)d_out;
  const int B = out_size;              // 256 rows
  const int V = in_sizes[0] / B;       // 50257

  // workspace layout (no zeroing needed — every slot read is written first)
  char* ws = (char*)d_ws;
  int*   scnt  = (int*)ws;                                           // B*S i32
  float* svals = (float*)(ws + (size_t)B * S_CHUNKS * 4);            // B*S*SEG f32
  int*   sidxs = (int*)(ws + (size_t)B * S_CHUNKS * 4 +
                        (size_t)B * S_CHUNKS * SEG * 4);             // B*S*SEG i32

  hipLaunchKernelGGL(k_pass1, dim3(S_CHUNKS, B), dim3(PB), 0, stream,
                     logits, topk, scnt, svals, sidxs, V);
  hipLaunchKernelGGL(k_tail, dim3(B), dim3(TB), 0, stream,
                     scnt, svals, sidxs, topk, out, V);
}

// Round 5
// 112.534 us; speedup vs baseline: 1.3093x; 1.3093x over previous
//
#include <hip/hip_runtime.h>
#include <stdint.h>

// Sampler: temperature -> top-k -> top-p -> softmax -> multinomial (threefry)
// Round-5: exact selection via ballot binary-search (registers, no barriers),
// sort only the ~51 survivors. Round-4 post-mortem: O(n^2) rank-sort over
// ~600 candidates was LDS-issue-bound (~30us of broadcast ds_reads).

#define BINS     4096
#define S_CHUNKS 8
#define PB       256
#define SEG      256
#define TB       64               // tail: one wave per row
#define CAPN     1024             // tail candidate capacity (realistic ~410)
#define SLOTS    (CAPN / TB)      // 16 register key slots per lane
#define WCAP     256              // survivor capacity (realistic ~51)
#define TOPP     0.9f
#define TOPT_F   8.0f
#define OK8      0xC1000000u      // orderKey(8.0f)

// Order-preserving float -> uint map (ascending float == ascending uint)
__device__ __forceinline__ unsigned orderKey(float x) {
  unsigned u = __float_as_uint(x);
  return (u & 0x80000000u) ? ~u : (u | 0x80000000u);
}

// JAX threefry2x32 (20 rounds), exact.
__device__ __forceinline__ void threefry2x32(unsigned k0, unsigned k1,
                                             unsigned x0, unsigned x1,
                                             unsigned &o0, unsigned &o1) {
  unsigned k2 = k0 ^ k1 ^ 0x1BD11BDAu;
  x0 += k0; x1 += k1;
#define TFR(rr) { x0 += x1; x1 = (x1 << (rr)) | (x1 >> (32 - (rr))); x1 ^= x0; }
  TFR(13) TFR(15) TFR(26) TFR(6)
  x0 += k1; x1 += k2 + 1u;
  TFR(17) TFR(29) TFR(16) TFR(24)
  x0 += k2; x1 += k0 + 2u;
  TFR(13) TFR(15) TFR(26) TFR(6)
  x0 += k0; x1 += k1 + 3u;
  TFR(17) TFR(29) TFR(16) TFR(24)
  x0 += k1; x1 += k2 + 4u;
  TFR(13) TFR(15) TFR(26) TFR(6)
  x0 += k2; x1 += k0 + 5u;
#undef TFR
  o0 = x0; o1 = x1;
}

// ---- Kernel 1: stream-collect >=8.0, wave0 ballot-select exact local kth ----
__global__ __launch_bounds__(PB) void k_pass1(
    const float* __restrict__ logits, const int* __restrict__ topk_ptr,
    int* __restrict__ scnt, float* __restrict__ svals, int* __restrict__ sidxs,
    int V) {
  __shared__ unsigned hist[BINS];   // fallback only (16 KB)
  __shared__ unsigned psum[PB];     // fallback only
  __shared__ float    lval[SEG];
  __shared__ int      lidx[SEG];
  __shared__ unsigned lcnt, ocnt, s_thr;
  __shared__ int      s_bstar, s_g;

  const int row = blockIdx.y, chunk = blockIdx.x, tid = threadIdx.x;
  const float* __restrict__ rp = logits + (size_t)row * (size_t)V;
  const float4* __restrict__ rp4 = (const float4*)rp;
  const int V4 = V >> 2;
  const int beg = (int)((long long)chunk * V4 / S_CHUNKS);
  const int end = (int)((long long)(chunk + 1) * V4 / S_CHUNKS);
  const bool last = (chunk == S_CHUNKS - 1);
  const int rembeg = V4 << 2;
  const int sb = row * S_CHUNKS + chunk;
  float* __restrict__ ov = svals + (size_t)sb * SEG;
  int*   __restrict__ oi = sidxs + (size_t)sb * SEG;

  if (tid == 0) { lcnt = 0u; ocnt = 0u; }
  __syncthreads();

  // ---- scan (HBM): optimistic collect of x >= 8.0 ----
  for (int i = beg + tid; i < end; i += PB) {
    float4 v = rp4[i];
    float vv[4] = {v.x, v.y, v.z, v.w};
#pragma unroll
    for (int c = 0; c < 4; ++c) {
      if (vv[c] >= TOPT_F) {
        unsigned pos = atomicAdd(&lcnt, 1u);
        if (pos < SEG) { lval[pos] = vv[c]; lidx[pos] = (i << 2) + c; }
      }
    }
  }
  if (last) {
    for (int i = rembeg + tid; i < V; i += PB) {
      float x = rp[i];
      if (x >= TOPT_F) {
        unsigned pos = atomicAdd(&lcnt, 1u);
        if (pos < SEG) { lval[pos] = x; lidx[pos] = i; }
      }
    }
  }
  __syncthreads();

  int k = topk_ptr[0];
  if (k < 1) k = 1;
  if (k > V) k = V;
  const int ec = (end - beg) * 4 + (last ? (V - rembeg) : 0);
  const int keff = (k < ec) ? k : ec;

  const unsigned total = lcnt;
  const bool fast = (total >= (unsigned)keff) && (total <= (unsigned)SEG);

  if (fast) {
    // wave-0 ballot binary search: max T with count(key >= T) >= keff
    if (tid < 64) {
      unsigned key[SEG / 64];
#pragma unroll
      for (int t = 0; t < SEG / 64; ++t) {
        int i = tid + t * 64;
        key[t] = (i < (int)total) ? orderKey(lval[i]) : 0u;
      }
      unsigned lo = 1u, hi = 0xFFFFFFFFu;
      while (lo < hi) {
        unsigned mid = lo + ((hi - lo + 1u) >> 1);
        int c = 0;
#pragma unroll
        for (int t = 0; t < SEG / 64; ++t)
          c += __popcll(__ballot(key[t] >= mid));
        if (c >= keff) lo = mid; else hi = mid - 1u;
      }
      // 4-ULP tie margin must stay inside the buffered (>=8.0) range
      if (tid == 0) s_thr = (lo >= OK8 + 4u) ? lo - 4u : 0u;
    }
    __syncthreads();
    if (s_thr != 0u) {
      const unsigned thr = s_thr;
      for (int i = tid; i < (int)total; i += PB) {
        float x = lval[i];
        if (orderKey(x) >= thr) {
          unsigned pos = atomicAdd(&ocnt, 1u);
          ov[pos] = x;                 // pos < total <= SEG
          oi[pos] = lidx[i];
        }
      }
      __syncthreads();
      if (tid == 0) scnt[sb] = (int)ocnt;
      return;
    }
    // demoted: fall through to full-hist fallback
  }

  // ---- fallback: full-chunk histogram (L2-warm re-read) ----
  for (int i = tid; i < BINS; i += PB) hist[i] = 0u;
  __syncthreads();
  for (int i = beg + tid; i < end; i += PB) {
    float4 v = rp4[i];
    atomicAdd(&hist[orderKey(v.x) >> 20], 1u);
    atomicAdd(&hist[orderKey(v.y) >> 20], 1u);
    atomicAdd(&hist[orderKey(v.z) >> 20], 1u);
    atomicAdd(&hist[orderKey(v.w) >> 20], 1u);
  }
  if (last)
    for (int i = rembeg + tid; i < V; i += PB)
      atomicAdd(&hist[orderKey(rp[i]) >> 20], 1u);
  __syncthreads();

  const int C = BINS / PB;  // 16
  {
    unsigned s = 0;
#pragma unroll
    for (int j = 0; j < C; ++j) s += hist[tid * C + j];
    psum[tid] = s;
  }
  __syncthreads();
  for (int d = 1; d < PB; d <<= 1) {   // reverse inclusive scan
    unsigned v = psum[tid];
    unsigned w = (tid + d < PB) ? psum[tid + d] : 0u;
    __syncthreads();
    psum[tid] = v + w;
    __syncthreads();
  }
  if (psum[tid] >= (unsigned)keff &&
      (tid == PB - 1 || psum[tid + 1] < (unsigned)keff))
    s_g = tid;
  __syncthreads();
  if (tid == 0) {
    int g = s_g;
    unsigned cum = (g < PB - 1) ? psum[g + 1] : 0u;
    int bstar = g * C;
    for (int b = g * C + C - 1; b >= g * C; --b) {
      cum += hist[b];
      if (cum >= (unsigned)keff) { bstar = b; break; }
    }
    s_bstar = bstar;
  }
  __syncthreads();
  {
    unsigned uk = (unsigned)s_bstar << 20;
    const unsigned ukey = (uk >= 4u) ? uk - 4u : 0u;  // 4-ULP tie margin
    for (int i = beg + tid; i < end; i += PB) {
      float4 v = rp4[i];
      float vv[4] = {v.x, v.y, v.z, v.w};
#pragma unroll
      for (int c = 0; c < 4; ++c) {
        if (orderKey(vv[c]) >= ukey) {
          unsigned pos = atomicAdd(&ocnt, 1u);
          if (pos < SEG) { ov[pos] = vv[c]; oi[pos] = (i << 2) + c; }
        }
      }
    }
    if (last)
      for (int i = rembeg + tid; i < V; i += PB) {
        float x = rp[i];
        if (orderKey(x) >= ukey) {
          unsigned pos = atomicAdd(&ocnt, 1u);
          if (pos < SEG) { ov[pos] = x; oi[pos] = i; }
        }
      }
    __syncthreads();
    if (tid == 0) {
      unsigned t = ocnt;
      scnt[sb] = (int)((t > (unsigned)SEG) ? (unsigned)SEG : t);
    }
  }
}

// ---- Kernel 2: one wave/row — ballot-select global kth, sort ~51, sample ----
__global__ __launch_bounds__(TB) void k_tail(
    const int* __restrict__ scnt, const float* __restrict__ svals,
    const int* __restrict__ sidxs, const int* __restrict__ topk_ptr,
    int* __restrict__ out, int V) {
  __shared__ float sval[CAPN];   // scaled candidates
  __shared__ int   sidx[CAPN];
  __shared__ float wv[WCAP];     // survivors (arrival order)
  __shared__ int   wi[WCAP];
  __shared__ float ovv[WCAP];    // sorted survivors
  __shared__ int   oii[WCAP];
  __shared__ float ev[WCAP];
  __shared__ short ord[WCAP];
  __shared__ int   s_off[S_CHUNKS + 1];
  __shared__ unsigned s_wc;
  __shared__ int   s_K;
  __shared__ float s_S2, s_r;

  const int row = blockIdx.x, tid = threadIdx.x;
  int k = topk_ptr[0];
  if (k < 1) k = 1;
  if (k > V) k = V;

  if (tid == 0) {
    int off = 0;
    for (int c = 0; c < S_CHUNKS; ++c) { s_off[c] = off; off += scnt[row * S_CHUNKS + c]; }
    s_off[S_CHUNKS] = off;
    s_wc = 0u;
  }
  __syncthreads();
  int n = s_off[S_CHUNKS];
  if (n > CAPN) n = CAPN;
  if (n == 0) { if (tid == 0) out[row] = V; return; }

  // gather + temperature scale (IEEE div, matches ref)
  for (int c = 0; c < S_CHUNKS; ++c) {
    int o = s_off[c];
    if (o >= CAPN) break;
    int cn = s_off[c + 1] - o;
    if (o + cn > CAPN) cn = CAPN - o;
    const float* __restrict__ gv = svals + (size_t)(row * S_CHUNKS + c) * SEG;
    const int*   __restrict__ gi = sidxs + (size_t)(row * S_CHUNKS + c) * SEG;
    for (int i = tid; i < cn; i += TB) {
      sval[o + i] = gv[i] / 0.8f;
      sidx[o + i] = gi[i];
    }
  }
  __syncthreads();

  // cache scaled keys in registers (16 slots/lane, no barriers below)
  unsigned key[SLOTS];
#pragma unroll
  for (int t = 0; t < SLOTS; ++t) {
    int i = tid + t * TB;
    key[t] = (i < n) ? orderKey(sval[i]) : 0u;
  }

  // ballot binary search: kv = kk-th largest scaled key (exact)
  const int kk = (k < n) ? k : n;
  unsigned lo = 1u, hi = 0xFFFFFFFFu;
  while (lo < hi) {
    unsigned mid = lo + ((hi - lo + 1u) >> 1);
    int c = 0;
#pragma unroll
    for (int t = 0; t < SLOTS; ++t)
      c += __popcll(__ballot(key[t] >= mid));
    if (c >= kk) lo = mid; else hi = mid - 1u;
  }
  const unsigned kv = lo;

  // survivors = {key >= kv} == top-k plus all ties at the kth scaled value
#pragma unroll
  for (int t = 0; t < SLOTS; ++t) {
    int i = tid + t * TB;
    if (i < n && key[t] >= kv) {
      unsigned pos = atomicAdd(&s_wc, 1u);
      if (pos < WCAP) { wv[pos] = sval[i]; wi[pos] = sidx[i]; }
    }
  }
  __syncthreads();
  int ns = (int)s_wc;
  if (ns > WCAP) ns = WCAP;

  // rank-sort survivors: scaled desc, index asc (== ref stable argsort)
  for (int i = tid; i < ns; i += TB) {
    float v = wv[i];
    int   id = wi[i];
    int   rk = 0;
    for (int j = 0; j < ns; ++j) {
      float vj = wv[j];
      rk += (vj > v) || (vj == v && wi[j] < id);
    }
    ovv[rk] = v;
    oii[rk] = id;
  }
  __syncthreads();

  // e = exp(v - max)
  const float mx = ovv[0];
  for (int i = tid; i < ns; i += TB) ev[i] = expf(ovv[i] - mx);
  __syncthreads();

  // top-p keep-prefix + RNG (serial, exact accumulation order)
  if (tid == 0) {
    float S = 0.f;
    for (int i = 0; i < ns; ++i) S += ev[i];
    float c = 0.f;
    int K = ns;
    for (int i = 0; i < ns; ++i) {
      if (i > 0 && c > TOPP) { K = i; break; }  // remove[i] = cdf[i-1] > p
      c += ev[i] / S;
    }
    float S2 = 0.f;
    for (int i = 0; i < K; ++i) S2 += ev[i];
    s_K = K;
    s_S2 = S2;

    // r = uniform from fold_in(key(0), 1), partitionable threefry path
    unsigned kk0, kk1, o0, o1;
    threefry2x32(0u, 0u, 0u, 1u, kk0, kk1);
    threefry2x32(kk0, kk1, 0u, (unsigned)row, o0, o1);
    unsigned bits = o0 ^ o1;
    float r = __uint_as_float((bits >> 9) | 0x3F800000u) - 1.0f;
    s_r = (r < 0.f) ? 0.f : r;
  }
  __syncthreads();
  const int K = s_K;

  // rank kept tokens by original index
  for (int i = tid; i < K; i += TB) {
    int id = oii[i];
    int rk = 0;
    for (int j = 0; j < K; ++j) rk += (oii[j] < id);
    ord[rk] = (short)i;
  }
  __syncthreads();

  // inverse-CDF sample in original-index order
  if (tid == 0) {
    const float S2 = s_S2;
    const float rr = s_r;
    float c = 0.f;
    int ans = V;  // matches sum(cdf <= r) when r beyond total mass
    for (int t = 0; t < K; ++t) {
      int i = ord[t];
      c += ev[i] / S2;
      if (c > rr) { ans = oii[i]; break; }
    }
    out[row] = ans;
  }
}

extern "C" void kernel_launch(void* const* d_in, const int* in_sizes, int n_in,
                              void* d_out, int out_size, void* d_ws, size_t ws_size,
                              hipStream_t stream) {
  const float* logits = (const float*)d_in[0];
  const int*   topk   = (const int*)d_in[1];
  int*         out    = (int*)d_out;
  const int B = out_size;              // 256 rows
  const int V = in_sizes[0] / B;       // 50257

  // workspace layout (no zeroing needed — every slot read is written first)
  char* ws = (char*)d_ws;
  int*   scnt  = (int*)ws;                                           // B*S i32
  float* svals = (float*)(ws + (size_t)B * S_CHUNKS * 4);            // B*S*SEG f32
  int*   sidxs = (int*)(ws + (size_t)B * S_CHUNKS * 4 +
                        (size_t)B * S_CHUNKS * SEG * 4);             // B*S*SEG i32

  hipLaunchKernelGGL(k_pass1, dim3(S_CHUNKS, B), dim3(PB), 0, stream,
                     logits, topk, scnt, svals, sidxs, V);
  hipLaunchKernelGGL(k_tail, dim3(B), dim3(TB), 0, stream,
                     scnt, svals, sidxs, topk, out, V);
}